// Round 1
// baseline (988.555 us; speedup 1.0000x reference)
//
#include <hip/hip_runtime.h>

#define NPTS  50000
#define NEDGE 800000
#define ICH   16
#define OCH   16
#define HID   64

// Exact GELU via Abramowitz-Stegun 7.1.26 erf approximation (|err| <= 1.5e-7).
// Branch-free: 1 rcp + 1 exp + ~10 FMA. Reference uses approximate=False gelu.
__device__ __forceinline__ float gelu_exact(float v) {
    const float INV_SQRT2 = 0.70710678118654752440f;
    float z  = v * INV_SQRT2;
    float az = fabsf(z);
    float t  = __builtin_amdgcn_rcpf(fmaf(0.3275911f, az, 1.0f));
    float poly = t * fmaf(t, fmaf(t, fmaf(t, fmaf(t, 1.061405429f, -1.453152027f),
                                          1.421413741f), -0.284496736f), 0.254829592f);
    float e  = __expf(-az * az);
    float er = fmaf(-poly, e, 1.0f);
    er = (z < 0.0f) ? -er : er;
    return 0.5f * v * (1.0f + er);
}

__global__ void zero_out_kernel(float* __restrict__ out, int n) {
    int i = blockIdx.x * blockDim.x + threadIdx.x;
    if (i < n) out[i] = 0.0f;
}

__global__ __launch_bounds__(256) void edge_kernel(
    const float* __restrict__ x,    // [NPTS*16]
    const float* __restrict__ pos,  // [NPTS*3]
    const int*   __restrict__ ei,   // [2*NEDGE]
    const float* __restrict__ W1,   // [6*64]
    const float* __restrict__ b1,   // [64]
    const float* __restrict__ Wh,   // [64*64]
    const float* __restrict__ bh,   // [64]
    const float* __restrict__ Wo,   // [64*256]
    const float* __restrict__ bo,   // [256]
    float* __restrict__ out)        // [NPTS*16]
{
    int e = blockIdx.x * 256 + threadIdx.x;
    if (e >= NEDGE) return;

    int src = ei[e];
    int dst = ei[NEDGE + e];
    // cheap in-range clamp (protects against index-dtype surprises)
    src = min(max(src, 0), NPTS - 1);
    dst = min(max(dst, 0), NPTS - 1);

    // positional encoding: [pos[src], pos[dst]]
    float pe[6];
    pe[0] = pos[src * 3 + 0];
    pe[1] = pos[src * 3 + 1];
    pe[2] = pos[src * 3 + 2];
    pe[3] = pos[dst * 3 + 0];
    pe[4] = pos[dst * 3 + 1];
    pe[5] = pos[dst * 3 + 2];

    // gather x[src] (64B aligned -> 4x float4)
    float xv[ICH];
    {
        const float4* xp = reinterpret_cast<const float4*>(x + src * ICH);
        float4 a = xp[0], b = xp[1], c = xp[2], d = xp[3];
        xv[0]=a.x; xv[1]=a.y; xv[2]=a.z; xv[3]=a.w;
        xv[4]=b.x; xv[5]=b.y; xv[6]=b.z; xv[7]=b.w;
        xv[8]=c.x; xv[9]=c.y; xv[10]=c.z; xv[11]=c.w;
        xv[12]=d.x; xv[13]=d.y; xv[14]=d.z; xv[15]=d.w;
    }

    // layer 1: h1 = gelu(pos_enc @ W1 + b1)   (static unroll, h1 in regs)
    float h1[HID];
#pragma unroll
    for (int j = 0; j < HID; ++j) {
        float acc = b1[j];
#pragma unroll
        for (int k = 0; k < 6; ++k)
            acc = fmaf(pe[k], W1[k * HID + j], acc);
        h1[j] = gelu_exact(acc);
    }

    // msg starts with the bo contribution: msg[o] = sum_i xv[i]*bo[i*16+o]
    float msg[OCH];
#pragma unroll
    for (int o = 0; o < OCH; ++o) msg[o] = 0.0f;
#pragma unroll
    for (int i = 0; i < ICH; ++i) {
#pragma unroll
        for (int o = 0; o < OCH; ++o)
            msg[o] = fmaf(xv[i], bo[i * OCH + o], msg[o]);
    }

    // fused layer2 + layer3 + einsum, rolled over hidden index k:
    //   h2k = gelu(bh[k] + sum_j h1[j]*Wh[j,k])
    //   msg[o] += (h2k * xv[i]) * Wo[k, i*16+o]
#pragma unroll 1
    for (int k = 0; k < HID; ++k) {
        float acc = bh[k];
#pragma unroll
        for (int j = 0; j < HID; ++j)
            acc = fmaf(h1[j], Wh[j * HID + k], acc);
        float h2k = gelu_exact(acc);

        const float* wrow = Wo + k * (ICH * OCH);
#pragma unroll
        for (int i = 0; i < ICH; ++i) {
            float hx = h2k * xv[i];
#pragma unroll
            for (int o = 0; o < OCH; ++o)
                msg[o] = fmaf(hx, wrow[i * OCH + o], msg[o]);
        }
    }

    // scatter-add into out[dst]
    float* op = out + dst * OCH;
#pragma unroll
    for (int o = 0; o < OCH; ++o)
        atomicAdd(op + o, msg[o]);
}

extern "C" void kernel_launch(void* const* d_in, const int* in_sizes, int n_in,
                              void* d_out, int out_size, void* d_ws, size_t ws_size,
                              hipStream_t stream) {
    const float* x   = (const float*)d_in[0];
    const float* pos = (const float*)d_in[1];
    const int*   ei  = (const int*)d_in[2];
    const float* W1  = (const float*)d_in[3];
    const float* b1  = (const float*)d_in[4];
    const float* Wh  = (const float*)d_in[5];
    const float* bh  = (const float*)d_in[6];
    const float* Wo  = (const float*)d_in[7];
    const float* bo  = (const float*)d_in[8];
    float* out = (float*)d_out;

    zero_out_kernel<<<(out_size + 255) / 256, 256, 0, stream>>>(out, out_size);
    edge_kernel<<<(NEDGE + 255) / 256, 256, 0, stream>>>(
        x, pos, ei, W1, b1, Wh, bh, Wo, bo, out);
}

// Round 2
// 224.957 us; speedup vs baseline: 4.3944x; 4.3944x over previous
//
#include <hip/hip_runtime.h>

#define NPTS  50000
#define NEDGE 800000
#define ICH   16
#define OCH   16
#define HID   64

typedef short bf16x8 __attribute__((ext_vector_type(8)));
typedef float f32x4  __attribute__((ext_vector_type(4)));

// Exact GELU via Abramowitz-Stegun 7.1.26 erf (|err| <= 1.5e-7), branch-free.
__device__ __forceinline__ float gelu_exact(float v) {
    const float INV_SQRT2 = 0.70710678118654752440f;
    float z  = v * INV_SQRT2;
    float az = fabsf(z);
    float t  = __builtin_amdgcn_rcpf(fmaf(0.3275911f, az, 1.0f));
    float poly = t * fmaf(t, fmaf(t, fmaf(t, fmaf(t, 1.061405429f, -1.453152027f),
                                          1.421413741f), -0.284496736f), 0.254829592f);
    float e  = __expf(-az * az);
    float er = fmaf(-poly, e, 1.0f);
    er = (z < 0.0f) ? -er : er;
    return 0.5f * v * (1.0f + er);
}

// fp32 -> bf16 round-to-nearest-even
__device__ __forceinline__ unsigned short f2bf(float f) {
    unsigned u = __builtin_bit_cast(unsigned, f);
    unsigned r = (u + 0x7FFFu + ((u >> 16) & 1u)) >> 16;
    return (unsigned short)r;
}

__global__ void zero_out_kernel(float* __restrict__ out, int n) {
    int i = blockIdx.x * blockDim.x + threadIdx.x;
    if (i < n) out[i] = 0.0f;
}

// Block = 256 threads = 4 waves. Each wave processes 4 tiles of 16 edges.
// Grid = 800000 / 256 = 3125 blocks, exact.
__global__ __launch_bounds__(256, 2) void edge_mfma_kernel(
    const float* __restrict__ x,    // [NPTS*16]
    const float* __restrict__ pos,  // [NPTS*3]
    const int*   __restrict__ ei,   // [2*NEDGE]
    const float* __restrict__ W1,   // [6*64]
    const float* __restrict__ b1,   // [64]
    const float* __restrict__ Wh,   // [64*64]
    const float* __restrict__ bh,   // [64]
    const float* __restrict__ Wo,   // [64*256]
    const float* __restrict__ bo,   // [256]
    float* __restrict__ out)        // [NPTS*16]
{
    // Transposed bf16 weights: Wt[n][k] so B-fragments are contiguous in k.
    // Row stride padded (+8 / to 40) for bank spread; all frag reads 16B-aligned.
    __shared__ __align__(16) unsigned short WhT[64 * 72];    //  9216 B
    __shared__ __align__(16) unsigned short WoT[256 * 72];   // 36864 B
    __shared__ __align__(16) unsigned short W1T[64 * 40];    //  5120 B (k zero-padded 6->32)
    __shared__ float b1s[64];
    __shared__ float bhs[64];
    __shared__ float bos[256];
    __shared__ __align__(16) unsigned short hbuf[4][16 * 72]; // per-wave H1/H2 tile (bf16)
    __shared__ float xs[4][16 * 17];                          // per-wave x[src] tile, pad 17
    __shared__ int   dsts[4][16];

    const int tid = threadIdx.x;

    // ---- stage weights (once per block) ----
    for (int idx = tid; idx < 64 * 64; idx += 256) {           // WhT[n][k] = Wh[k][n]
        int k = idx >> 6, n = idx & 63;
        WhT[n * 72 + k] = f2bf(Wh[idx]);
    }
    for (int idx = tid; idx < 256 * 64; idx += 256) {          // WoT[n][k] = Wo[k][n]
        int k = idx >> 8, n = idx & 255;
        WoT[n * 72 + k] = f2bf(Wo[idx]);
    }
    for (int idx = tid; idx < 64 * 40; idx += 256) {           // W1T[n][k] = (k<6)?W1[k][n]:0
        int n = idx / 40, k = idx - n * 40;
        W1T[idx] = (k < 6) ? f2bf(W1[k * 64 + n]) : (unsigned short)0;
    }
    if (tid < 64)  { b1s[tid] = b1[tid]; bhs[tid] = bh[tid]; }
    if (tid < 256) { bos[tid] = bo[tid]; }
    __syncthreads();

    const int wave = tid >> 6;
    const int lane = tid & 63;
    const int grp  = lane >> 4;   // 0..3
    const int er   = lane & 15;   // edge-in-tile for loads / col index for frags

    unsigned short* hb = hbuf[wave];
    float*          xw = xs[wave];
    int*            dw = dsts[wave];

#pragma unroll 1
    for (int t = 0; t < 4; ++t) {
        const int tile  = blockIdx.x * 16 + wave * 4 + t;
        const int ebase = tile * 16;

        // ---- per-edge loads (lane's edge = er; 4-way redundant across grp) ----
        int s = ei[ebase + er];
        int d = ei[NEDGE + ebase + er];
        s = min(max(s, 0), NPTS - 1);
        d = min(max(d, 0), NPTS - 1);
        if (grp == 0) dw[er] = d;

        // stage x[src]: lane writes quarter `grp` of row `er`
        {
            const float4 v = *reinterpret_cast<const float4*>(x + (size_t)s * 16 + grp * 4);
            xw[er * 17 + grp * 4 + 0] = v.x;
            xw[er * 17 + grp * 4 + 1] = v.y;
            xw[er * 17 + grp * 4 + 2] = v.z;
            xw[er * 17 + grp * 4 + 3] = v.w;
        }

        // positional encoding of edge `er` (only grp==0 lanes feed the A-fragment)
        float pe0 = pos[s * 3 + 0], pe1 = pos[s * 3 + 1], pe2 = pos[s * 3 + 2];
        float pe3 = pos[d * 3 + 0], pe4 = pos[d * 3 + 1], pe5 = pos[d * 3 + 2];

        // ---- layer 1 via MFMA: A = PE[16 x 32(zero-pad)], B = W1T, N=64 ----
        // A-frag: lane holds rows er, k = grp*8+j  -> only grp==0 lanes nonzero (k=0..5)
        bf16x8 ape;
        ape[0] = (grp == 0) ? (short)f2bf(pe0) : (short)0;
        ape[1] = (grp == 0) ? (short)f2bf(pe1) : (short)0;
        ape[2] = (grp == 0) ? (short)f2bf(pe2) : (short)0;
        ape[3] = (grp == 0) ? (short)f2bf(pe3) : (short)0;
        ape[4] = (grp == 0) ? (short)f2bf(pe4) : (short)0;
        ape[5] = (grp == 0) ? (short)f2bf(pe5) : (short)0;
        ape[6] = 0;
        ape[7] = 0;

#pragma unroll
        for (int nt = 0; nt < 4; ++nt) {
            bf16x8 bfr = *reinterpret_cast<bf16x8*>(&W1T[(nt * 16 + er) * 40 + grp * 8]);
            f32x4 c = {0.f, 0.f, 0.f, 0.f};
            c = __builtin_amdgcn_mfma_f32_16x16x32_bf16(ape, bfr, c, 0, 0, 0);
            // C/D: row = grp*4+r (edge), col = nt*16+er (hidden j)
            float b1v = b1s[nt * 16 + er];
#pragma unroll
            for (int r = 0; r < 4; ++r) {
                float h = gelu_exact(c[r] + b1v);
                hb[(grp * 4 + r) * 72 + nt * 16 + er] = f2bf(h);
            }
        }

        // ---- A1 fragments from hbuf: row = er, k = ktile*32 + grp*8 + j ----
        bf16x8 a10 = *reinterpret_cast<bf16x8*>(&hb[er * 72 +  0 + grp * 8]);
        bf16x8 a11 = *reinterpret_cast<bf16x8*>(&hb[er * 72 + 32 + grp * 8]);

        // ---- layer 2: H2 = gelu(H1 @ Wh + bh), N=64 in 4 tiles ----
        f32x4 acc2[4];
#pragma unroll
        for (int nt = 0; nt < 4; ++nt) {
            bf16x8 b0 = *reinterpret_cast<bf16x8*>(&WhT[(nt * 16 + er) * 72 +  0 + grp * 8]);
            bf16x8 b1f = *reinterpret_cast<bf16x8*>(&WhT[(nt * 16 + er) * 72 + 32 + grp * 8]);
            f32x4 c = {0.f, 0.f, 0.f, 0.f};
            c = __builtin_amdgcn_mfma_f32_16x16x32_bf16(a10, b0,  c, 0, 0, 0);
            c = __builtin_amdgcn_mfma_f32_16x16x32_bf16(a11, b1f, c, 0, 0, 0);
            acc2[nt] = c;
        }
#pragma unroll
        for (int nt = 0; nt < 4; ++nt) {
            float bhv = bhs[nt * 16 + er];
#pragma unroll
            for (int r = 0; r < 4; ++r) {
                float h2 = gelu_exact(acc2[nt][r] + bhv);
                hb[(grp * 4 + r) * 72 + nt * 16 + er] = f2bf(h2);
            }
        }

        // ---- A2 fragments ----
        bf16x8 a20 = *reinterpret_cast<bf16x8*>(&hb[er * 72 +  0 + grp * 8]);
        bf16x8 a21 = *reinterpret_cast<bf16x8*>(&hb[er * 72 + 32 + grp * 8]);

        // ---- layer 3 + einsum fused: N-tile i == input channel i ----
        // msg[e, o=er] += x[e,i] * (H2@Wo)[e, i*16+o] + x[e,i]*bo[i*16+o]
        float msg[4] = {0.f, 0.f, 0.f, 0.f};
#pragma unroll 4
        for (int i = 0; i < 16; ++i) {
            bf16x8 b0 = *reinterpret_cast<bf16x8*>(&WoT[(i * 16 + er) * 72 +  0 + grp * 8]);
            bf16x8 b1f = *reinterpret_cast<bf16x8*>(&WoT[(i * 16 + er) * 72 + 32 + grp * 8]);
            f32x4 c = {0.f, 0.f, 0.f, 0.f};
            c = __builtin_amdgcn_mfma_f32_16x16x32_bf16(a20, b0,  c, 0, 0, 0);
            c = __builtin_amdgcn_mfma_f32_16x16x32_bf16(a21, b1f, c, 0, 0, 0);
            float bov = bos[i * 16 + er];
#pragma unroll
            for (int r = 0; r < 4; ++r) {
                msg[r] = fmaf(xw[(grp * 4 + r) * 17 + i], c[r] + bov, msg[r]);
            }
        }

        // ---- scatter-add: lane covers edges grp*4+r, channel er ----
#pragma unroll
        for (int r = 0; r < 4; ++r) {
            atomicAdd(out + (size_t)dw[grp * 4 + r] * 16 + er, msg[r]);
        }
    }
}

extern "C" void kernel_launch(void* const* d_in, const int* in_sizes, int n_in,
                              void* d_out, int out_size, void* d_ws, size_t ws_size,
                              hipStream_t stream) {
    const float* x   = (const float*)d_in[0];
    const float* pos = (const float*)d_in[1];
    const int*   ei  = (const int*)d_in[2];
    const float* W1  = (const float*)d_in[3];
    const float* b1  = (const float*)d_in[4];
    const float* Wh  = (const float*)d_in[5];
    const float* bh  = (const float*)d_in[6];
    const float* Wo  = (const float*)d_in[7];
    const float* bo  = (const float*)d_in[8];
    float* out = (float*)d_out;

    zero_out_kernel<<<(out_size + 255) / 256, 256, 0, stream>>>(out, out_size);
    edge_mfma_kernel<<<NEDGE / 256, 256, 0, stream>>>(
        x, pos, ei, W1, b1, Wh, bh, Wo, bo, out);
}